// Round 4
// baseline (1587.604 us; speedup 1.0000x reference)
//
#include <hip/hip_runtime.h>
#include <hip/hip_bf16.h>

// Problem constants (from reference)
#define S_DIM 8192
#define H_DIM 7168
#define D0_DIM 1536
#define D1_DIM 576
#define N_DIM 2112          // D0 + D1
#define R_DIM 64
#define LA_WIDTH 128        // 2 * R

// Extended-K fused layout: K' = H + 128 (64 lora cols per slice, complementary
// halves zeroed in Wext so one GEMM computes base + LoRA-B contribution).
#define K_EXT 7296
#define NT32 228            // K_EXT / 32 k-blocks
#define N_PAD 2176          // 17 * 128
#define KSPLIT 8
#define KCHUNK 896          // H_DIM / KSPLIT

// Tiled-swizzled staging layout for xe/we (verified round 2: zero LDS bank
// conflicts in main GEMM):
//   [rblock = row/16][kblock = k/32][64 slots][8 shorts]  (1 KB per block)
//   slot = (row%16)*4 + cphys,  cphys = (k%32)/8 ^ (((row%16)>>3)&1)<<1
#define XE_RB 512           // S_DIM / 16
#define WE_RB 136           // N_PAD / 16

#define CONV_BLKS 256
#define CONV_ITEMS (WE_RB * NT32 * 64)   // 1,984,512 16B-items (all of we)

typedef __attribute__((ext_vector_type(4))) float f32x4;
typedef __attribute__((ext_vector_type(8))) short bf16x8;
typedef __attribute__((ext_vector_type(4))) short bf16x4;

__device__ __forceinline__ short f2bf(float f) {
    union { __hip_bfloat16 h; short s; } u;
    u.h = __float2bfloat16(f);
    return u.s;
}

__device__ __forceinline__ bf16x8 pack8(f32x4 a, f32x4 b) {
    bf16x8 r;
    r[0] = f2bf(a[0]); r[1] = f2bf(a[1]); r[2] = f2bf(a[2]); r[3] = f2bf(a[3]);
    r[4] = f2bf(b[0]); r[5] = f2bf(b[1]); r[6] = f2bf(b[2]); r[7] = f2bf(b[3]);
    return r;
}

__device__ __forceinline__ void gload_lds16(const short* g, short* l) {
    __builtin_amdgcn_global_load_lds(
        (const __attribute__((address_space(1))) unsigned int*)(const void*)g,
        (__attribute__((address_space(3))) unsigned int*)(void*)l, 16, 0, 0);
}

// ---------------------------------------------------------------------------
// fused_stage1: blocks [0, CONV_BLKS) grid-stride the FULL we conversion
// (W main cols, LoRA-B cols, zeroed pad rows); blocks [CONV_BLKS, +512) run
// the lora_a GEMM with fused x->bf16 conversion into xe.
// (Round-3 verified: staging wall-cost is pinned at ~400 us regardless of
// implementation -> left untouched this round.)
// ---------------------------------------------------------------------------
__global__ __launch_bounds__(256, 2)
void fused_stage1(const float* __restrict__ x, const float* __restrict__ W,
                  const float* __restrict__ A, const float* __restrict__ Bbuf,
                  float* __restrict__ la, short* __restrict__ xe,
                  short* __restrict__ we) {
    if (blockIdx.x < CONV_BLKS) {
        // ---- we conversion, grid-strided ----
        const unsigned base0 = blockIdx.x * 256u + threadIdx.x;
#pragma unroll 1
        for (int itr = 0; itr < 31; ++itr) {
            unsigned id = base0 + (unsigned)itr * (CONV_BLKS * 256u);
            if (id < CONV_ITEMS) {
                unsigned rb  = id / 14592u;          // NT32*64
                unsigned rem = id % 14592u;
                unsigned kb  = rem >> 6, sl = rem & 63u;
                unsigned r16 = sl >> 2;
                unsigned c   = (sl & 3u) ^ (((r16 >> 3) & 1u) << 1);
                unsigned row = rb * 16u + r16;
                bf16x8 v = {};
                if (row < N_DIM) {
                    if (kb < 224u) {
                        unsigned k = kb * 32u + c * 8u;
                        const float* p = W + (size_t)row * H_DIM + k;
                        f32x4 a = *(const f32x4*)p;
                        f32x4 b = *(const f32x4*)(p + 4);
                        v = pack8(a, b);
                    } else {
                        unsigned kl = (kb - 224u) * 32u + c * 8u;   // 0..127
                        const bool s1 = row >= D0_DIM;
                        const unsigned lo = s1 ? 64u : 0u;
                        if (kl >= lo && kl < lo + 64u) {
                            const float* p = Bbuf + ((size_t)(s1 ? 1u : 0u) * D0_DIM +
                                                     (row - (s1 ? D0_DIM : 0u))) * R_DIM + (kl - lo);
                            f32x4 a = *(const f32x4*)p;
                            f32x4 b = *(const f32x4*)(p + 4);
                            v = pack8(a, b);
                        }
                    }
                }
                *(bf16x8*)(we + ((size_t)rb * NT32 + kb) * 512u + sl * 8u) = v;
            }
        }
        return;
    }

    // ---- lora_a + convert_x ----
    __shared__ __align__(16) short sX[2][128 * 40];
    __shared__ __align__(16) short sA[2][128 * 40];

    const int bx = blockIdx.x - CONV_BLKS;     // 0..511
    const int tid = threadIdx.x;
    const int m0 = (bx >> 3) * 128;
    const int k0 = (bx & 7) * KCHUNK;
    const int wave = tid >> 6, lane = tid & 63;
    const int wm = (wave & 1) * 64, wn = (wave >> 1) * 64;
    const int fr = lane & 15, fq = lane >> 4;

    f32x4 acc[4][4] = {};

    const int srow = tid >> 1, shalf = (tid & 1) * 16;
    const float* xP = x + (size_t)(m0 + srow) * H_DIM + k0 + shalf;
    const float* aP = A + (size_t)srow * H_DIM + k0 + shalf;

    // tiled-swizzled xe destination
    const unsigned rbx = (unsigned)(m0 + srow) >> 4;
    const unsigned r16 = (unsigned)srow & 15u;
    const unsigned kb0 = (unsigned)k0 >> 5;
    const unsigned c0  = (unsigned)shalf >> 3;       // 0 or 2
    const unsigned sx  = ((r16 >> 3) & 1u) << 1;
    const unsigned sl0 = r16 * 4u + (c0 ^ sx);
    const unsigned sl1 = r16 * 4u + ((c0 + 1u) ^ sx);
    short* xeB = xe + ((size_t)rbx * NT32 + kb0) * 512u;

    const int swoff = srow * 40 + shalf;
    const int xr_off = (wm + fr) * 40 + fq * 8;
    const int ar_off = (wn + fr) * 40 + fq * 8;

    // preload iter 0
    f32x4 cx0 = *(const f32x4*)(xP);
    f32x4 cx1 = *(const f32x4*)(xP + 4);
    f32x4 cx2 = *(const f32x4*)(xP + 8);
    f32x4 cx3 = *(const f32x4*)(xP + 12);
    f32x4 ca0 = *(const f32x4*)(aP);
    f32x4 ca1 = *(const f32x4*)(aP + 4);
    f32x4 ca2 = *(const f32x4*)(aP + 8);
    f32x4 ca3 = *(const f32x4*)(aP + 12);
    f32x4 nx0 = {}, nx1 = {}, nx2 = {}, nx3 = {};
    f32x4 na0 = {}, na1 = {}, na2 = {}, na3 = {};

#pragma unroll 1
    for (int it = 0; it < KCHUNK / 32; ++it) {
        if (it < KCHUNK / 32 - 1) {
            const float* px = xP + (it + 1) * 32;
            const float* pa = aP + (it + 1) * 32;
            nx0 = *(const f32x4*)(px);
            nx1 = *(const f32x4*)(px + 4);
            nx2 = *(const f32x4*)(px + 8);
            nx3 = *(const f32x4*)(px + 12);
            na0 = *(const f32x4*)(pa);
            na1 = *(const f32x4*)(pa + 4);
            na2 = *(const f32x4*)(pa + 8);
            na3 = *(const f32x4*)(pa + 12);
        }
        bf16x8 px0 = pack8(cx0, cx1), px1 = pack8(cx2, cx3);
        bf16x8 pa0 = pack8(ca0, ca1), pa1 = pack8(ca2, ca3);

        // fused convert_x: tiled-swizzled store to xe
        *(bf16x8*)(xeB + (size_t)it * 512 + sl0 * 8u) = px0;
        *(bf16x8*)(xeB + (size_t)it * 512 + sl1 * 8u) = px1;

        short* bX = &sX[it & 1][0];
        short* bA = &sA[it & 1][0];
        *(bf16x8*)(bX + swoff) = px0; *(bf16x8*)(bX + swoff + 8) = px1;
        *(bf16x8*)(bA + swoff) = pa0; *(bf16x8*)(bA + swoff + 8) = pa1;

        asm volatile("s_waitcnt lgkmcnt(0)" ::: "memory");
        __builtin_amdgcn_s_barrier();
        __builtin_amdgcn_sched_barrier(0);

        bf16x8 af[4], bfg[4];
#pragma unroll
        for (int i = 0; i < 4; ++i) af[i] = *(const bf16x8*)(bX + xr_off + i * 640);
#pragma unroll
        for (int i = 0; i < 4; ++i) bfg[i] = *(const bf16x8*)(bA + ar_off + i * 640);
#pragma unroll
        for (int mi = 0; mi < 4; ++mi)
#pragma unroll
            for (int ni = 0; ni < 4; ++ni)
                acc[mi][ni] = __builtin_amdgcn_mfma_f32_16x16x32_bf16(
                    af[mi], bfg[ni], acc[mi][ni], 0, 0, 0);

        cx0 = nx0; cx1 = nx1; cx2 = nx2; cx3 = nx3;
        ca0 = na0; ca1 = na1; ca2 = na2; ca3 = na3;
    }

    // partial-sum epilogue: fp32 atomics into la (8 k-split adders/elem)
#pragma unroll
    for (int ni = 0; ni < 4; ++ni) {
        const int col = wn + ni * 16 + fr;
#pragma unroll
        for (int mi = 0; mi < 4; ++mi) {
            const int row = m0 + wm + mi * 16 + fq * 4;
#pragma unroll
            for (int r = 0; r < 4; ++r)
                atomicAdd(&la[(size_t)(row + r) * LA_WIDTH + col], acc[mi][ni][r]);
        }
    }
}

// la_to_xe: la fp32 [S][128] -> bf16 -> xe kblocks 224..227 (swizzled slots)
__global__ __launch_bounds__(256)
void la_to_xe(const float* __restrict__ la, short* __restrict__ xe) {
    unsigned id = blockIdx.x * 256u + threadIdx.x;   // < 8192*16
    unsigned row = id >> 4, c8 = (id & 15u) * 8u;
    const float* p = la + (size_t)row * LA_WIDTH + c8;
    f32x4 s0 = *(const f32x4*)(p);
    f32x4 s1 = *(const f32x4*)(p + 4);
    unsigned rbx = row >> 4, r16 = row & 15u;
    unsigned kb = 224u + (c8 >> 5);
    unsigned cc = (c8 >> 3) & 3u;
    unsigned sl = r16 * 4u + (cc ^ (((r16 >> 3) & 1u) << 1));
    *(bf16x8*)(xe + ((size_t)rbx * NT32 + kb) * 512u + sl * 8u) = pack8(s0, s1);
}

// ---------------------------------------------------------------------------
// main_gemm_tiled: out = xext @ Wext^T + bias  (K = 7296 includes LoRA-B)
// ROUND 4: ring-2 LDS (48 KB) -> 3 blocks/CU. 544 blocks <= 768 resident
// slots: the whole grid is co-resident (round-3's 32-block straggler tail,
// ~30% of the dispatch, is eliminated) and 12 waves/CU hide per-phase
// latency across blocks. Ring-2 requires a second barrier per K-step
// (reads must retire before the DMA re-targets the buffer being read):
//   vmcnt(6) -> barrier -> ds_read -> lgkmcnt(0) -> barrier
//   -> issue DMA(kt+2 -> buf kt&1) -> MFMA
// Pipeline depth unchanged: 2 tiles / 12 loads in flight, vmcnt(6) counted.
// ---------------------------------------------------------------------------
__global__ __launch_bounds__(256, 3)
void main_gemm_tiled(const short* __restrict__ xe, const short* __restrict__ we,
                     const float* __restrict__ bias, float* __restrict__ out) {
    __shared__ __align__(16) short lds[2 * 12288];   // 2 bufs x (A 16KB | B 8KB)

    const int tid = threadIdx.x;
    const int bx = blockIdx.x;                 // 0..543
    const int xcd = bx & 7, p = bx >> 3;
    const int tile = xcd * 68 + p;             // 544 = 8 * 68 exactly
    const int m0 = (tile / 17) * 256;
    const int n0 = (tile % 17) * 128;

    const int wave = tid >> 6, lane = tid & 63;
    const int wm = (wave & 1) * 128;
    const int wn = (wave >> 1) * 64;
    const int fr = lane & 15, fq = lane >> 4;

    f32x4 acc[8][4] = {};

    // per-tile staging: 24 x 1KB blocks (A rblocks 0..15, B rblocks 0..7);
    // wave w issues 6 contiguous-source global_load_lds.
    const short* gp[6];
    int ldoff[6];
    {
        const short* xe_pan = xe + (size_t)(m0 >> 4) * NT32 * 512 + lane * 8;
        const short* we_pan = we + (size_t)(n0 >> 4) * NT32 * 512 + lane * 8;
#pragma unroll
        for (int i = 0; i < 6; ++i) {
            const int idx = wave * 6 + i;
            if (idx < 16) { gp[i] = xe_pan + (size_t)idx * NT32 * 512; ldoff[i] = idx * 512; }
            else          { gp[i] = we_pan + (size_t)(idx - 16) * NT32 * 512; ldoff[i] = 8192 + (idx - 16) * 512; }
        }
    }

    // swizzled fragment read offsets (shorts): row*32 + (fq ^ ((row>>3)&1)<<1)*8
    const int swz  = (fq ^ ((fr >> 3) << 1)) * 8;
    const int aoff = (wm + fr) * 32 + swz;
    const int boff = 8192 + (wn + fr) * 32 + swz;

    // prologue: tile 0 -> buf 0, tile 1 -> buf 1 (12 loads in flight)
#pragma unroll
    for (int i = 0; i < 6; ++i) gload_lds16(gp[i], lds + ldoff[i]);
#pragma unroll
    for (int i = 0; i < 6; ++i) gload_lds16(gp[i] + 512, lds + 12288 + ldoff[i]);

#pragma unroll 1
    for (int kt = 0; kt < NT32; ++kt) {
        const int b = kt & 1;
        // counted wait: tile kt's 6 loads are the oldest of 12 outstanding
        asm volatile("s_waitcnt vmcnt(6)" ::: "memory");
        __builtin_amdgcn_s_barrier();
        __builtin_amdgcn_sched_barrier(0);

        const short* pa = lds + b * 12288 + aoff;
        const short* pb = lds + b * 12288 + boff;
        bf16x8 af[8], brf[4];
#pragma unroll
        for (int m = 0; m < 8; ++m) af[m] = *(const bf16x8*)(pa + m * 512);
#pragma unroll
        for (int n = 0; n < 4; ++n) brf[n] = *(const bf16x8*)(pb + n * 512);

        // all our ds_reads retired -> after the next barrier, buf b may be
        // overwritten by the kt+2 DMA
        asm volatile("s_waitcnt lgkmcnt(0)" ::: "memory");
        __builtin_amdgcn_sched_barrier(0);
        __builtin_amdgcn_s_barrier();

        int tt = kt + 2; if (tt >= NT32) tt -= NT32;   // tail: dummy re-stage
#pragma unroll
        for (int i = 0; i < 6; ++i)
            gload_lds16(gp[i] + (size_t)tt * 512, lds + b * 12288 + ldoff[i]);
        __builtin_amdgcn_sched_barrier(0);

        __builtin_amdgcn_s_setprio(1);
#pragma unroll
        for (int m = 0; m < 8; ++m)
#pragma unroll
            for (int n = 0; n < 4; ++n)
                acc[m][n] = __builtin_amdgcn_mfma_f32_16x16x32_bf16(
                    af[m], brf[n], acc[m][n], 0, 0, 0);
        __builtin_amdgcn_s_setprio(0);
        __builtin_amdgcn_sched_barrier(0);
    }
    asm volatile("s_waitcnt vmcnt(0)" ::: "memory");

    // epilogue: + bias, fp32 store. C/D: col = lane&15, row = fq*4 + r
#pragma unroll
    for (int n = 0; n < 4; ++n) {
        const int col = n0 + wn + n * 16 + fr;
        if (col < N_DIM) {
            const float bv = bias[col];
#pragma unroll
            for (int m = 0; m < 8; ++m) {
                const int row = m0 + wm + m * 16 + fq * 4;
#pragma unroll
                for (int r = 0; r < 4; ++r)
                    out[(size_t)(row + r) * N_DIM + col] = acc[m][n][r] + bv;
            }
        }
    }
}

// ===========================================================================
// Fallback (round-1 proven path) if workspace is too small for bf16 staging
// ===========================================================================
__global__ __launch_bounds__(256, 2)
void lora_a_gemm(const float* __restrict__ x, const float* __restrict__ Abuf,
                 float* __restrict__ la) {
    __shared__ __align__(16) short sX[32 * 40];
    __shared__ __align__(16) short sA[128 * 40];
    const int tid = threadIdx.x;
    const int m0 = blockIdx.x * 32;
    const int wave = tid >> 6, lane = tid & 63;
    const int fr = lane & 15, fq = lane >> 4;
    const int wn = wave * 32;
    f32x4 acc[2][2] = {};
    const int xrow = tid >> 3, xcol = (tid & 7) * 4;
    const float* xP = x + (size_t)(m0 + xrow) * H_DIM + xcol;
    short* sXw = sX + xrow * 40 + xcol;
    const int arow = tid >> 1, ahalf = (tid & 1) * 16;
    const float* aP = Abuf + (size_t)arow * H_DIM + ahalf;
    short* sAw = sA + arow * 40 + ahalf;
    const short* sXr = sX + fr * 40 + fq * 8;
    const short* sAr = sA + (wn + fr) * 40 + fq * 8;
    for (int kt = 0; kt < H_DIM / 32; ++kt) {
        f32x4 xv = *(const f32x4*)(xP + kt * 32);
        f32x4 a0 = *(const f32x4*)(aP + kt * 32);
        f32x4 a1 = *(const f32x4*)(aP + kt * 32 + 4);
        f32x4 a2 = *(const f32x4*)(aP + kt * 32 + 8);
        f32x4 a3 = *(const f32x4*)(aP + kt * 32 + 12);
        bf16x4 xs;
        xs[0] = f2bf(xv[0]); xs[1] = f2bf(xv[1]);
        xs[2] = f2bf(xv[2]); xs[3] = f2bf(xv[3]);
        bf16x8 as0 = pack8(a0, a1), as1 = pack8(a2, a3);
        __syncthreads();
        *(bf16x4*)(sXw) = xs;
        *(bf16x8*)(sAw) = as0;
        *(bf16x8*)(sAw + 8) = as1;
        __syncthreads();
        bf16x8 xf0 = *(const bf16x8*)(sXr);
        bf16x8 xf1 = *(const bf16x8*)(sXr + 16 * 40);
        bf16x8 af0 = *(const bf16x8*)(sAr);
        bf16x8 af1 = *(const bf16x8*)(sAr + 16 * 40);
        acc[0][0] = __builtin_amdgcn_mfma_f32_16x16x32_bf16(xf0, af0, acc[0][0], 0, 0, 0);
        acc[0][1] = __builtin_amdgcn_mfma_f32_16x16x32_bf16(xf0, af1, acc[0][1], 0, 0, 0);
        acc[1][0] = __builtin_amdgcn_mfma_f32_16x16x32_bf16(xf1, af0, acc[1][0], 0, 0, 0);
        acc[1][1] = __builtin_amdgcn_mfma_f32_16x16x32_bf16(xf1, af1, acc[1][1], 0, 0, 0);
    }
#pragma unroll
    for (int ni = 0; ni < 2; ++ni) {
        const int col = wn + ni * 16 + fr;
#pragma unroll
        for (int mi = 0; mi < 2; ++mi) {
            const int row = m0 + mi * 16 + fq * 4;
#pragma unroll
            for (int r = 0; r < 4; ++r)
                la[(size_t)(row + r) * LA_WIDTH + col] = acc[mi][ni][r];
        }
    }
}

#define LDS_STRIDE 40
__global__ __launch_bounds__(256, 2)
void main_gemm(const float* __restrict__ x, const float* __restrict__ W,
               const float* __restrict__ bias, const float* __restrict__ Bbuf,
               const float* __restrict__ la, float* __restrict__ out) {
    __shared__ __align__(16) short sA[128 * LDS_STRIDE];
    __shared__ __align__(16) short sB[128 * LDS_STRIDE];
    const int tid = threadIdx.x;
    const int n0 = blockIdx.x * 128, m0 = blockIdx.y * 128;
    const int wave = tid >> 6, lane = tid & 63;
    const int wm = (wave & 1) * 64, wn = (wave >> 1) * 64;
    const int fr = lane & 15, fq = lane >> 4;
    f32x4 acc[4][4] = {};
    const int srow = tid >> 1, shalf = (tid & 1) * 16;
    const float* xP = x + (size_t)(m0 + srow) * H_DIM + shalf;
    const int wRow = n0 + srow;
    const bool wValid = wRow < N_DIM;
    const float* wP = W + (size_t)wRow * H_DIM + shalf;
    const int slice = (n0 >= D0_DIM) ? 1 : 0;
    const int oCol = wRow - slice * D0_DIM;
    const bool bValid = wValid && (oCol < (slice ? D1_DIM : D0_DIM));
    const float* laP = la + (size_t)(m0 + srow) * LA_WIDTH + slice * R_DIM + shalf;
    const float* bP = Bbuf + ((size_t)slice * D0_DIM + oCol) * R_DIM + shalf;
    short* sAw = sA + srow * LDS_STRIDE + shalf;
    short* sBw = sB + srow * LDS_STRIDE + shalf;
    const short* sAr = sA + (wm + fr) * LDS_STRIDE + fq * 8;
    const short* sBr = sB + (wn + fr) * LDS_STRIDE + fq * 8;
    const int KT = H_DIM / 32;
    for (int it = 0; it < KT + 2; ++it) {
        const float *pa, *pb;
        bool vb;
        if (it < KT) { pa = xP + it * 32; pb = wP + it * 32; vb = wValid; }
        else { const int lt = it - KT; pa = laP + lt * 32; pb = bP + lt * 32; vb = bValid; }
        f32x4 a0 = *(const f32x4*)(pa);
        f32x4 a1 = *(const f32x4*)(pa + 4);
        f32x4 a2 = *(const f32x4*)(pa + 8);
        f32x4 a3 = *(const f32x4*)(pa + 12);
        f32x4 z = {0.f, 0.f, 0.f, 0.f};
        f32x4 b0 = z, b1 = z, b2 = z, b3 = z;
        if (vb) {
            b0 = *(const f32x4*)(pb); b1 = *(const f32x4*)(pb + 4);
            b2 = *(const f32x4*)(pb + 8); b3 = *(const f32x4*)(pb + 12);
        }
        bf16x8 pa0 = pack8(a0, a1), pa1 = pack8(a2, a3);
        bf16x8 pb0 = pack8(b0, b1), pb1 = pack8(b2, b3);
        __syncthreads();
        *(bf16x8*)(sAw) = pa0; *(bf16x8*)(sAw + 8) = pa1;
        *(bf16x8*)(sBw) = pb0; *(bf16x8*)(sBw + 8) = pb1;
        __syncthreads();
        bf16x8 af[4], bfg[4];
#pragma unroll
        for (int i = 0; i < 4; ++i) af[i] = *(const bf16x8*)(sAr + i * 16 * LDS_STRIDE);
#pragma unroll
        for (int i = 0; i < 4; ++i) bfg[i] = *(const bf16x8*)(sBr + i * 16 * LDS_STRIDE);
#pragma unroll
        for (int mi = 0; mi < 4; ++mi)
#pragma unroll
            for (int ni = 0; ni < 4; ++ni)
                acc[mi][ni] = __builtin_amdgcn_mfma_f32_16x16x32_bf16(
                    af[mi], bfg[ni], acc[mi][ni], 0, 0, 0);
    }
#pragma unroll
    for (int ni = 0; ni < 4; ++ni) {
        const int col = n0 + wn + ni * 16 + fr;
        if (col < N_DIM) {
            const float bv = bias[col];
#pragma unroll
            for (int mi = 0; mi < 4; ++mi) {
                const int row = m0 + wm + mi * 16 + fq * 4;
#pragma unroll
                for (int r = 0; r < 4; ++r)
                    out[(size_t)(row + r) * N_DIM + col] = acc[mi][ni][r] + bv;
            }
        }
    }
}

extern "C" void kernel_launch(void* const* d_in, const int* in_sizes, int n_in,
                              void* d_out, int out_size, void* d_ws, size_t ws_size,
                              hipStream_t stream) {
    const float* x    = (const float*)d_in[0];
    const float* W    = (const float*)d_in[1];
    const float* bias = (const float*)d_in[2];
    const float* A    = (const float*)d_in[3];
    const float* B    = (const float*)d_in[4];
    float* out = (float*)d_out;

    const size_t xe_bytes = (size_t)XE_RB * NT32 * 1024;   // 119,537,664
    const size_t we_bytes = (size_t)WE_RB * NT32 * 1024;   //  31,752,192
    const size_t la_bytes = (size_t)S_DIM * LA_WIDTH * 4;  //   4,194,304

    if (ws_size >= xe_bytes + we_bytes) {
        short* xe = (short*)d_ws;
        short* we = (short*)((char*)d_ws + xe_bytes);
        // la scratch lives in the HEAD of the output buffer: zeroed here,
        // accumulated by fused_stage1, consumed by la_to_xe, then fully
        // overwritten by main_gemm_tiled's epilogue.
        float* la = (float*)d_out;

        hipMemsetAsync(d_out, 0, la_bytes, stream);
        fused_stage1<<<dim3(CONV_BLKS + 512), dim3(256), 0, stream>>>(
            x, W, A, B, la, xe, we);
        la_to_xe<<<dim3(S_DIM * 16 / 256), dim3(256), 0, stream>>>(la, xe);
        main_gemm_tiled<<<dim3(32 * 17), dim3(256), 0, stream>>>(xe, we, bias, out);
    } else {
        float* la = (float*)d_ws;   // 4 MB scratch
        lora_a_gemm<<<dim3(S_DIM / 32), dim3(256), 0, stream>>>(x, A, la);
        main_gemm<<<dim3(N_DIM / 128 + 1, S_DIM / 128), dim3(256), 0, stream>>>(
            x, W, bias, B, la, out);
    }
}

// Round 5
// 703.912 us; speedup vs baseline: 2.2554x; 2.2554x over previous
//
#include <hip/hip_runtime.h>
#include <hip/hip_bf16.h>

// Problem constants (from reference)
#define S_DIM 8192
#define H_DIM 7168
#define D0_DIM 1536
#define D1_DIM 576
#define N_DIM 2112          // D0 + D1
#define R_DIM 64
#define LA_WIDTH 128        // 2 * R

// Extended-K fused layout: K' = H + 128 (64 lora cols per slice, complementary
// halves zeroed in Wext so one GEMM computes base + LoRA-B contribution).
#define K_EXT 7296
#define NT32 228            // K_EXT / 32 k-blocks
#define N_PAD 2176          // 17 * 128
#define KSPLIT 8
#define KCHUNK 896          // H_DIM / KSPLIT

// Tiled-swizzled staging layout for xe/we (verified round 2: zero LDS bank
// conflicts in main GEMM):
//   [rblock = row/16][kblock = k/32][64 slots][8 shorts]  (1 KB per block)
//   slot = (row%16)*4 + cphys,  cphys = (k%32)/8 ^ (((row%16)>>3)&1)<<1
#define XE_RB 512           // S_DIM / 16
#define WE_RB 136           // N_PAD / 16

#define CONV_BLKS 256
#define CONV_ITEMS (WE_RB * NT32 * 64)   // 1,984,512 16B-items (all of we)

typedef __attribute__((ext_vector_type(4))) float f32x4;
typedef __attribute__((ext_vector_type(8))) short bf16x8;
typedef __attribute__((ext_vector_type(4))) short bf16x4;

__device__ __forceinline__ short f2bf(float f) {
    union { __hip_bfloat16 h; short s; } u;
    u.h = __float2bfloat16(f);
    return u.s;
}

__device__ __forceinline__ bf16x8 pack8(f32x4 a, f32x4 b) {
    bf16x8 r;
    r[0] = f2bf(a[0]); r[1] = f2bf(a[1]); r[2] = f2bf(a[2]); r[3] = f2bf(a[3]);
    r[4] = f2bf(b[0]); r[5] = f2bf(b[1]); r[6] = f2bf(b[2]); r[7] = f2bf(b[3]);
    return r;
}

__device__ __forceinline__ void gload_lds16(const short* g, short* l) {
    __builtin_amdgcn_global_load_lds(
        (const __attribute__((address_space(1))) unsigned int*)(const void*)g,
        (__attribute__((address_space(3))) unsigned int*)(void*)l, 16, 0, 0);
}

// ---------------------------------------------------------------------------
// fused_stage1: blocks [0, CONV_BLKS) grid-stride the FULL we conversion
// (W main cols, LoRA-B cols, zeroed pad rows); blocks [CONV_BLKS, +512) run
// the lora_a GEMM with fused x->bf16 conversion into xe.
// (Round-3 verified: staging wall-cost is pinned at ~400 us regardless of
// implementation -> left untouched.)
// ---------------------------------------------------------------------------
__global__ __launch_bounds__(256, 2)
void fused_stage1(const float* __restrict__ x, const float* __restrict__ W,
                  const float* __restrict__ A, const float* __restrict__ Bbuf,
                  float* __restrict__ la, short* __restrict__ xe,
                  short* __restrict__ we) {
    if (blockIdx.x < CONV_BLKS) {
        // ---- we conversion, grid-strided ----
        const unsigned base0 = blockIdx.x * 256u + threadIdx.x;
#pragma unroll 1
        for (int itr = 0; itr < 31; ++itr) {
            unsigned id = base0 + (unsigned)itr * (CONV_BLKS * 256u);
            if (id < CONV_ITEMS) {
                unsigned rb  = id / 14592u;          // NT32*64
                unsigned rem = id % 14592u;
                unsigned kb  = rem >> 6, sl = rem & 63u;
                unsigned r16 = sl >> 2;
                unsigned c   = (sl & 3u) ^ (((r16 >> 3) & 1u) << 1);
                unsigned row = rb * 16u + r16;
                bf16x8 v = {};
                if (row < N_DIM) {
                    if (kb < 224u) {
                        unsigned k = kb * 32u + c * 8u;
                        const float* p = W + (size_t)row * H_DIM + k;
                        f32x4 a = *(const f32x4*)p;
                        f32x4 b = *(const f32x4*)(p + 4);
                        v = pack8(a, b);
                    } else {
                        unsigned kl = (kb - 224u) * 32u + c * 8u;   // 0..127
                        const bool s1 = row >= D0_DIM;
                        const unsigned lo = s1 ? 64u : 0u;
                        if (kl >= lo && kl < lo + 64u) {
                            const float* p = Bbuf + ((size_t)(s1 ? 1u : 0u) * D0_DIM +
                                                     (row - (s1 ? D0_DIM : 0u))) * R_DIM + (kl - lo);
                            f32x4 a = *(const f32x4*)p;
                            f32x4 b = *(const f32x4*)(p + 4);
                            v = pack8(a, b);
                        }
                    }
                }
                *(bf16x8*)(we + ((size_t)rb * NT32 + kb) * 512u + sl * 8u) = v;
            }
        }
        return;
    }

    // ---- lora_a + convert_x ----
    __shared__ __align__(16) short sX[2][128 * 40];
    __shared__ __align__(16) short sA[2][128 * 40];

    const int bx = blockIdx.x - CONV_BLKS;     // 0..511
    const int tid = threadIdx.x;
    const int m0 = (bx >> 3) * 128;
    const int k0 = (bx & 7) * KCHUNK;
    const int wave = tid >> 6, lane = tid & 63;
    const int wm = (wave & 1) * 64, wn = (wave >> 1) * 64;
    const int fr = lane & 15, fq = lane >> 4;

    f32x4 acc[4][4] = {};

    const int srow = tid >> 1, shalf = (tid & 1) * 16;
    const float* xP = x + (size_t)(m0 + srow) * H_DIM + k0 + shalf;
    const float* aP = A + (size_t)srow * H_DIM + k0 + shalf;

    // tiled-swizzled xe destination
    const unsigned rbx = (unsigned)(m0 + srow) >> 4;
    const unsigned r16 = (unsigned)srow & 15u;
    const unsigned kb0 = (unsigned)k0 >> 5;
    const unsigned c0  = (unsigned)shalf >> 3;       // 0 or 2
    const unsigned sx  = ((r16 >> 3) & 1u) << 1;
    const unsigned sl0 = r16 * 4u + (c0 ^ sx);
    const unsigned sl1 = r16 * 4u + ((c0 + 1u) ^ sx);
    short* xeB = xe + ((size_t)rbx * NT32 + kb0) * 512u;

    const int swoff = srow * 40 + shalf;
    const int xr_off = (wm + fr) * 40 + fq * 8;
    const int ar_off = (wn + fr) * 40 + fq * 8;

    // preload iter 0
    f32x4 cx0 = *(const f32x4*)(xP);
    f32x4 cx1 = *(const f32x4*)(xP + 4);
    f32x4 cx2 = *(const f32x4*)(xP + 8);
    f32x4 cx3 = *(const f32x4*)(xP + 12);
    f32x4 ca0 = *(const f32x4*)(aP);
    f32x4 ca1 = *(const f32x4*)(aP + 4);
    f32x4 ca2 = *(const f32x4*)(aP + 8);
    f32x4 ca3 = *(const f32x4*)(aP + 12);
    f32x4 nx0 = {}, nx1 = {}, nx2 = {}, nx3 = {};
    f32x4 na0 = {}, na1 = {}, na2 = {}, na3 = {};

#pragma unroll 1
    for (int it = 0; it < KCHUNK / 32; ++it) {
        if (it < KCHUNK / 32 - 1) {
            const float* px = xP + (it + 1) * 32;
            const float* pa = aP + (it + 1) * 32;
            nx0 = *(const f32x4*)(px);
            nx1 = *(const f32x4*)(px + 4);
            nx2 = *(const f32x4*)(px + 8);
            nx3 = *(const f32x4*)(px + 12);
            na0 = *(const f32x4*)(pa);
            na1 = *(const f32x4*)(pa + 4);
            na2 = *(const f32x4*)(pa + 8);
            na3 = *(const f32x4*)(pa + 12);
        }
        bf16x8 px0 = pack8(cx0, cx1), px1 = pack8(cx2, cx3);
        bf16x8 pa0 = pack8(ca0, ca1), pa1 = pack8(ca2, ca3);

        // fused convert_x: tiled-swizzled store to xe
        *(bf16x8*)(xeB + (size_t)it * 512 + sl0 * 8u) = px0;
        *(bf16x8*)(xeB + (size_t)it * 512 + sl1 * 8u) = px1;

        short* bX = &sX[it & 1][0];
        short* bA = &sA[it & 1][0];
        *(bf16x8*)(bX + swoff) = px0; *(bf16x8*)(bX + swoff + 8) = px1;
        *(bf16x8*)(bA + swoff) = pa0; *(bf16x8*)(bA + swoff + 8) = pa1;

        asm volatile("s_waitcnt lgkmcnt(0)" ::: "memory");
        __builtin_amdgcn_s_barrier();
        __builtin_amdgcn_sched_barrier(0);

        bf16x8 af[4], bfg[4];
#pragma unroll
        for (int i = 0; i < 4; ++i) af[i] = *(const bf16x8*)(bX + xr_off + i * 640);
#pragma unroll
        for (int i = 0; i < 4; ++i) bfg[i] = *(const bf16x8*)(bA + ar_off + i * 640);
#pragma unroll
        for (int mi = 0; mi < 4; ++mi)
#pragma unroll
            for (int ni = 0; ni < 4; ++ni)
                acc[mi][ni] = __builtin_amdgcn_mfma_f32_16x16x32_bf16(
                    af[mi], bfg[ni], acc[mi][ni], 0, 0, 0);

        cx0 = nx0; cx1 = nx1; cx2 = nx2; cx3 = nx3;
        ca0 = na0; ca1 = na1; ca2 = na2; ca3 = na3;
    }

    // partial-sum epilogue: fp32 atomics into la (8 k-split adders/elem)
#pragma unroll
    for (int ni = 0; ni < 4; ++ni) {
        const int col = wn + ni * 16 + fr;
#pragma unroll
        for (int mi = 0; mi < 4; ++mi) {
            const int row = m0 + wm + mi * 16 + fq * 4;
#pragma unroll
            for (int r = 0; r < 4; ++r)
                atomicAdd(&la[(size_t)(row + r) * LA_WIDTH + col], acc[mi][ni][r]);
        }
    }
}

// la_to_xe: la fp32 [S][128] -> bf16 -> xe kblocks 224..227 (swizzled slots)
__global__ __launch_bounds__(256)
void la_to_xe(const float* __restrict__ la, short* __restrict__ xe) {
    unsigned id = blockIdx.x * 256u + threadIdx.x;   // < 8192*16
    unsigned row = id >> 4, c8 = (id & 15u) * 8u;
    const float* p = la + (size_t)row * LA_WIDTH + c8;
    f32x4 s0 = *(const f32x4*)(p);
    f32x4 s1 = *(const f32x4*)(p + 4);
    unsigned rbx = row >> 4, r16 = row & 15u;
    unsigned kb = 224u + (c8 >> 5);
    unsigned cc = (c8 >> 3) & 3u;
    unsigned sl = r16 * 4u + (cc ^ (((r16 >> 3) & 1u) << 1));
    *(bf16x8*)(xe + ((size_t)rbx * NT32 + kb) * 512u + sl * 8u) = pack8(s0, s1);
}

// ---------------------------------------------------------------------------
// main_gemm_tiled: out = xext @ Wext^T + bias  (K = 7296 includes LoRA-B)
// ROUND 5: ring-2 LDS (48 KB), __launch_bounds__(256, 2).
// Round-4 diagnosis: (256,3) made the allocator target ~6 waves/SIMD ->
// VGPR capped at 84 -> acc[8][4] (128 regs) spilled to scratch ->
// WRITE_SIZE 1.76 GB, 4.3x regression. The cap was unnecessary: residency
// comes from real resources. With (256,2) this body allocates ~116 VGPR
// (rounds 1-3 verified, no spill) -> 4 waves/SIMD allowed; LDS 48 KB ->
// 3 blocks/CU. All 544 blocks co-resident (<= 768 slots): no straggler
// round, 12 waves/CU latency cover.
// Ring-2 schedule (round-4 verified correct):
//   vmcnt(6) -> barrier -> ds_read -> lgkmcnt(0) -> barrier
//   -> issue DMA(kt+2 -> buf kt&1) -> MFMA
// Pipeline depth: 2 tiles / 12 loads in flight, counted vmcnt, never 0.
// ---------------------------------------------------------------------------
__global__ __launch_bounds__(256, 2)
void main_gemm_tiled(const short* __restrict__ xe, const short* __restrict__ we,
                     const float* __restrict__ bias, float* __restrict__ out) {
    __shared__ __align__(16) short lds[2 * 12288];   // 2 bufs x (A 16KB | B 8KB)

    const int tid = threadIdx.x;
    const int bx = blockIdx.x;                 // 0..543
    const int xcd = bx & 7, p = bx >> 3;
    const int tile = xcd * 68 + p;             // 544 = 8 * 68 exactly
    const int m0 = (tile / 17) * 256;
    const int n0 = (tile % 17) * 128;

    const int wave = tid >> 6, lane = tid & 63;
    const int wm = (wave & 1) * 128;
    const int wn = (wave >> 1) * 64;
    const int fr = lane & 15, fq = lane >> 4;

    f32x4 acc[8][4] = {};

    // per-tile staging: 24 x 1KB blocks (A rblocks 0..15, B rblocks 0..7);
    // wave w issues 6 contiguous-source global_load_lds.
    const short* gp[6];
    int ldoff[6];
    {
        const short* xe_pan = xe + (size_t)(m0 >> 4) * NT32 * 512 + lane * 8;
        const short* we_pan = we + (size_t)(n0 >> 4) * NT32 * 512 + lane * 8;
#pragma unroll
        for (int i = 0; i < 6; ++i) {
            const int idx = wave * 6 + i;
            if (idx < 16) { gp[i] = xe_pan + (size_t)idx * NT32 * 512; ldoff[i] = idx * 512; }
            else          { gp[i] = we_pan + (size_t)(idx - 16) * NT32 * 512; ldoff[i] = 8192 + (idx - 16) * 512; }
        }
    }

    // swizzled fragment read offsets (shorts): row*32 + (fq ^ ((row>>3)&1)<<1)*8
    const int swz  = (fq ^ ((fr >> 3) << 1)) * 8;
    const int aoff = (wm + fr) * 32 + swz;
    const int boff = 8192 + (wn + fr) * 32 + swz;

    // prologue: tile 0 -> buf 0, tile 1 -> buf 1 (12 loads in flight)
#pragma unroll
    for (int i = 0; i < 6; ++i) gload_lds16(gp[i], lds + ldoff[i]);
#pragma unroll
    for (int i = 0; i < 6; ++i) gload_lds16(gp[i] + 512, lds + 12288 + ldoff[i]);

#pragma unroll 1
    for (int kt = 0; kt < NT32; ++kt) {
        const int b = kt & 1;
        // counted wait: tile kt's 6 loads are the oldest of 12 outstanding
        asm volatile("s_waitcnt vmcnt(6)" ::: "memory");
        __builtin_amdgcn_s_barrier();
        __builtin_amdgcn_sched_barrier(0);

        const short* pa = lds + b * 12288 + aoff;
        const short* pb = lds + b * 12288 + boff;
        bf16x8 af[8], brf[4];
#pragma unroll
        for (int m = 0; m < 8; ++m) af[m] = *(const bf16x8*)(pa + m * 512);
#pragma unroll
        for (int n = 0; n < 4; ++n) brf[n] = *(const bf16x8*)(pb + n * 512);

        // all our ds_reads retired -> after the next barrier, buf b may be
        // overwritten by the kt+2 DMA
        asm volatile("s_waitcnt lgkmcnt(0)" ::: "memory");
        __builtin_amdgcn_sched_barrier(0);
        __builtin_amdgcn_s_barrier();

        int tt = kt + 2; if (tt >= NT32) tt -= NT32;   // tail: dummy re-stage
#pragma unroll
        for (int i = 0; i < 6; ++i)
            gload_lds16(gp[i] + (size_t)tt * 512, lds + b * 12288 + ldoff[i]);
        __builtin_amdgcn_sched_barrier(0);

        __builtin_amdgcn_s_setprio(1);
#pragma unroll
        for (int m = 0; m < 8; ++m)
#pragma unroll
            for (int n = 0; n < 4; ++n)
                acc[m][n] = __builtin_amdgcn_mfma_f32_16x16x32_bf16(
                    af[m], brf[n], acc[m][n], 0, 0, 0);
        __builtin_amdgcn_s_setprio(0);
        __builtin_amdgcn_sched_barrier(0);
    }
    asm volatile("s_waitcnt vmcnt(0)" ::: "memory");

    // epilogue: + bias, fp32 store. C/D: col = lane&15, row = fq*4 + r
#pragma unroll
    for (int n = 0; n < 4; ++n) {
        const int col = n0 + wn + n * 16 + fr;
        if (col < N_DIM) {
            const float bv = bias[col];
#pragma unroll
            for (int m = 0; m < 8; ++m) {
                const int row = m0 + wm + m * 16 + fq * 4;
#pragma unroll
                for (int r = 0; r < 4; ++r)
                    out[(size_t)(row + r) * N_DIM + col] = acc[m][n][r] + bv;
            }
        }
    }
}

// ===========================================================================
// Fallback (round-1 proven path) if workspace is too small for bf16 staging
// ===========================================================================
__global__ __launch_bounds__(256, 2)
void lora_a_gemm(const float* __restrict__ x, const float* __restrict__ Abuf,
                 float* __restrict__ la) {
    __shared__ __align__(16) short sX[32 * 40];
    __shared__ __align__(16) short sA[128 * 40];
    const int tid = threadIdx.x;
    const int m0 = blockIdx.x * 32;
    const int wave = tid >> 6, lane = tid & 63;
    const int fr = lane & 15, fq = lane >> 4;
    const int wn = wave * 32;
    f32x4 acc[2][2] = {};
    const int xrow = tid >> 3, xcol = (tid & 7) * 4;
    const float* xP = x + (size_t)(m0 + xrow) * H_DIM + xcol;
    short* sXw = sX + xrow * 40 + xcol;
    const int arow = tid >> 1, ahalf = (tid & 1) * 16;
    const float* aP = Abuf + (size_t)arow * H_DIM + ahalf;
    short* sAw = sA + arow * 40 + ahalf;
    const short* sXr = sX + fr * 40 + fq * 8;
    const short* sAr = sA + (wn + fr) * 40 + fq * 8;
    for (int kt = 0; kt < H_DIM / 32; ++kt) {
        f32x4 xv = *(const f32x4*)(xP + kt * 32);
        f32x4 a0 = *(const f32x4*)(aP + kt * 32);
        f32x4 a1 = *(const f32x4*)(aP + kt * 32 + 4);
        f32x4 a2 = *(const f32x4*)(aP + kt * 32 + 8);
        f32x4 a3 = *(const f32x4*)(aP + kt * 32 + 12);
        bf16x4 xs;
        xs[0] = f2bf(xv[0]); xs[1] = f2bf(xv[1]);
        xs[2] = f2bf(xv[2]); xs[3] = f2bf(xv[3]);
        bf16x8 as0 = pack8(a0, a1), as1 = pack8(a2, a3);
        __syncthreads();
        *(bf16x4*)(sXw) = xs;
        *(bf16x8*)(sAw) = as0;
        *(bf16x8*)(sAw + 8) = as1;
        __syncthreads();
        bf16x8 xf0 = *(const bf16x8*)(sXr);
        bf16x8 xf1 = *(const bf16x8*)(sXr + 16 * 40);
        bf16x8 af0 = *(const bf16x8*)(sAr);
        bf16x8 af1 = *(const bf16x8*)(sAr + 16 * 40);
        acc[0][0] = __builtin_amdgcn_mfma_f32_16x16x32_bf16(xf0, af0, acc[0][0], 0, 0, 0);
        acc[0][1] = __builtin_amdgcn_mfma_f32_16x16x32_bf16(xf0, af1, acc[0][1], 0, 0, 0);
        acc[1][0] = __builtin_amdgcn_mfma_f32_16x16x32_bf16(xf1, af0, acc[1][0], 0, 0, 0);
        acc[1][1] = __builtin_amdgcn_mfma_f32_16x16x32_bf16(xf1, af1, acc[1][1], 0, 0, 0);
    }
#pragma unroll
    for (int ni = 0; ni < 2; ++ni) {
        const int col = wn + ni * 16 + fr;
#pragma unroll
        for (int mi = 0; mi < 2; ++mi) {
            const int row = m0 + mi * 16 + fq * 4;
#pragma unroll
            for (int r = 0; r < 4; ++r)
                la[(size_t)(row + r) * LA_WIDTH + col] = acc[mi][ni][r];
        }
    }
}

#define LDS_STRIDE 40
__global__ __launch_bounds__(256, 2)
void main_gemm(const float* __restrict__ x, const float* __restrict__ W,
               const float* __restrict__ bias, const float* __restrict__ Bbuf,
               const float* __restrict__ la, float* __restrict__ out) {
    __shared__ __align__(16) short sA[128 * LDS_STRIDE];
    __shared__ __align__(16) short sB[128 * LDS_STRIDE];
    const int tid = threadIdx.x;
    const int n0 = blockIdx.x * 128, m0 = blockIdx.y * 128;
    const int wave = tid >> 6, lane = tid & 63;
    const int wm = (wave & 1) * 64, wn = (wave >> 1) * 64;
    const int fr = lane & 15, fq = lane >> 4;
    f32x4 acc[4][4] = {};
    const int srow = tid >> 1, shalf = (tid & 1) * 16;
    const float* xP = x + (size_t)(m0 + srow) * H_DIM + shalf;
    const int wRow = n0 + srow;
    const bool wValid = wRow < N_DIM;
    const float* wP = W + (size_t)wRow * H_DIM + shalf;
    const int slice = (n0 >= D0_DIM) ? 1 : 0;
    const int oCol = wRow - slice * D0_DIM;
    const bool bValid = wValid && (oCol < (slice ? D1_DIM : D0_DIM));
    const float* laP = la + (size_t)(m0 + srow) * LA_WIDTH + slice * R_DIM + shalf;
    const float* bP = Bbuf + ((size_t)slice * D0_DIM + oCol) * R_DIM + shalf;
    short* sAw = sA + srow * LDS_STRIDE + shalf;
    short* sBw = sB + srow * LDS_STRIDE + shalf;
    const short* sAr = sA + (wm + fr) * LDS_STRIDE + fq * 8;
    const short* sBr = sB + (wn + fr) * LDS_STRIDE + fq * 8;
    const int KT = H_DIM / 32;
    for (int it = 0; it < KT + 2; ++it) {
        const float *pa, *pb;
        bool vb;
        if (it < KT) { pa = xP + it * 32; pb = wP + it * 32; vb = wValid; }
        else { const int lt = it - KT; pa = laP + lt * 32; pb = bP + lt * 32; vb = bValid; }
        f32x4 a0 = *(const f32x4*)(pa);
        f32x4 a1 = *(const f32x4*)(pa + 4);
        f32x4 a2 = *(const f32x4*)(pa + 8);
        f32x4 a3 = *(const f32x4*)(pa + 12);
        f32x4 z = {0.f, 0.f, 0.f, 0.f};
        f32x4 b0 = z, b1 = z, b2 = z, b3 = z;
        if (vb) {
            b0 = *(const f32x4*)(pb); b1 = *(const f32x4*)(pb + 4);
            b2 = *(const f32x4*)(pb + 8); b3 = *(const f32x4*)(pb + 12);
        }
        bf16x8 pa0 = pack8(a0, a1), pa1 = pack8(a2, a3);
        bf16x8 pb0 = pack8(b0, b1), pb1 = pack8(b2, b3);
        __syncthreads();
        *(bf16x8*)(sAw) = pa0; *(bf16x8*)(sAw + 8) = pa1;
        *(bf16x8*)(sBw) = pb0; *(bf16x8*)(sBw + 8) = pb1;
        __syncthreads();
        bf16x8 af[4], bfg[4];
#pragma unroll
        for (int i = 0; i < 4; ++i) af[i] = *(const bf16x8*)(sAr + i * 16 * LDS_STRIDE);
#pragma unroll
        for (int i = 0; i < 4; ++i) bfg[i] = *(const bf16x8*)(sBr + i * 16 * LDS_STRIDE);
#pragma unroll
        for (int mi = 0; mi < 4; ++mi)
#pragma unroll
            for (int ni = 0; ni < 4; ++ni)
                acc[mi][ni] = __builtin_amdgcn_mfma_f32_16x16x32_bf16(
                    af[mi], bfg[ni], acc[mi][ni], 0, 0, 0);
    }
#pragma unroll
    for (int ni = 0; ni < 4; ++ni) {
        const int col = n0 + wn + ni * 16 + fr;
        if (col < N_DIM) {
            const float bv = bias[col];
#pragma unroll
            for (int mi = 0; mi < 4; ++mi) {
                const int row = m0 + wm + mi * 16 + fq * 4;
#pragma unroll
                for (int r = 0; r < 4; ++r)
                    out[(size_t)(row + r) * N_DIM + col] = acc[mi][ni][r] + bv;
            }
        }
    }
}

extern "C" void kernel_launch(void* const* d_in, const int* in_sizes, int n_in,
                              void* d_out, int out_size, void* d_ws, size_t ws_size,
                              hipStream_t stream) {
    const float* x    = (const float*)d_in[0];
    const float* W    = (const float*)d_in[1];
    const float* bias = (const float*)d_in[2];
    const float* A    = (const float*)d_in[3];
    const float* B    = (const float*)d_in[4];
    float* out = (float*)d_out;

    const size_t xe_bytes = (size_t)XE_RB * NT32 * 1024;   // 119,537,664
    const size_t we_bytes = (size_t)WE_RB * NT32 * 1024;   //  31,752,192
    const size_t la_bytes = (size_t)S_DIM * LA_WIDTH * 4;  //   4,194,304

    if (ws_size >= xe_bytes + we_bytes) {
        short* xe = (short*)d_ws;
        short* we = (short*)((char*)d_ws + xe_bytes);
        // la scratch lives in the HEAD of the output buffer: zeroed here,
        // accumulated by fused_stage1, consumed by la_to_xe, then fully
        // overwritten by main_gemm_tiled's epilogue.
        float* la = (float*)d_out;

        hipMemsetAsync(d_out, 0, la_bytes, stream);
        fused_stage1<<<dim3(CONV_BLKS + 512), dim3(256), 0, stream>>>(
            x, W, A, B, la, xe, we);
        la_to_xe<<<dim3(S_DIM * 16 / 256), dim3(256), 0, stream>>>(la, xe);
        main_gemm_tiled<<<dim3(32 * 17), dim3(256), 0, stream>>>(xe, we, bias, out);
    } else {
        float* la = (float*)d_ws;   // 4 MB scratch
        lora_a_gemm<<<dim3(S_DIM / 32), dim3(256), 0, stream>>>(x, A, la);
        main_gemm<<<dim3(N_DIM / 128 + 1, S_DIM / 128), dim3(256), 0, stream>>>(
            x, W, bias, B, la, out);
    }
}

// Round 6
// 690.787 us; speedup vs baseline: 2.2983x; 1.0190x over previous
//
#include <hip/hip_runtime.h>
#include <hip/hip_bf16.h>

// Problem constants (from reference)
#define S_DIM 8192
#define H_DIM 7168
#define D0_DIM 1536
#define D1_DIM 576
#define N_DIM 2112          // D0 + D1
#define R_DIM 64
#define LA_WIDTH 128        // 2 * R

// Extended-K fused layout: K' = H + 128 (64 lora cols per slice, complementary
// halves zeroed in Wext so one GEMM computes base + LoRA-B contribution).
#define K_EXT 7296
#define NT32 228            // K_EXT / 32 k-blocks
#define N_PAD 2176          // 17 * 128
#define KSPLIT 8
#define KCHUNK 896          // H_DIM / KSPLIT

// Tiled-swizzled staging layout for xe/we (verified round 2: zero LDS bank
// conflicts in main GEMM):
//   [rblock = row/16][kblock = k/32][64 slots][8 shorts]  (1 KB per block)
//   slot = (row%16)*4 + cphys,  cphys = (k%32)/8 ^ (((row%16)>>3)&1)<<1
#define XE_RB 512           // S_DIM / 16
#define WE_RB 136           // N_PAD / 16

#define CONV_BLKS 256
#define CONV_ITEMS (WE_RB * NT32 * 64)   // 1,984,512 16B-items (all of we)

typedef __attribute__((ext_vector_type(4))) float f32x4;
typedef __attribute__((ext_vector_type(8))) short bf16x8;
typedef __attribute__((ext_vector_type(4))) short bf16x4;

__device__ __forceinline__ short f2bf(float f) {
    union { __hip_bfloat16 h; short s; } u;
    u.h = __float2bfloat16(f);
    return u.s;
}

__device__ __forceinline__ bf16x8 pack8(f32x4 a, f32x4 b) {
    bf16x8 r;
    r[0] = f2bf(a[0]); r[1] = f2bf(a[1]); r[2] = f2bf(a[2]); r[3] = f2bf(a[3]);
    r[4] = f2bf(b[0]); r[5] = f2bf(b[1]); r[6] = f2bf(b[2]); r[7] = f2bf(b[3]);
    return r;
}

__device__ __forceinline__ void gload_lds16(const short* g, short* l) {
    __builtin_amdgcn_global_load_lds(
        (const __attribute__((address_space(1))) unsigned int*)(const void*)g,
        (__attribute__((address_space(3))) unsigned int*)(void*)l, 16, 0, 0);
}

// ---------------------------------------------------------------------------
// fused_stage1: blocks [0, CONV_BLKS) grid-stride the FULL we conversion
// (W main cols, LoRA-B cols, zeroed pad rows); blocks [CONV_BLKS, +512) run
// the lora_a GEMM with fused x->bf16 conversion into xe.
// (Round-3 verified: staging wall-cost is pinned at ~400 us regardless of
// implementation -> left untouched.)
// ---------------------------------------------------------------------------
__global__ __launch_bounds__(256, 2)
void fused_stage1(const float* __restrict__ x, const float* __restrict__ W,
                  const float* __restrict__ A, const float* __restrict__ Bbuf,
                  float* __restrict__ la, short* __restrict__ xe,
                  short* __restrict__ we) {
    if (blockIdx.x < CONV_BLKS) {
        // ---- we conversion, grid-strided ----
        const unsigned base0 = blockIdx.x * 256u + threadIdx.x;
#pragma unroll 1
        for (int itr = 0; itr < 31; ++itr) {
            unsigned id = base0 + (unsigned)itr * (CONV_BLKS * 256u);
            if (id < CONV_ITEMS) {
                unsigned rb  = id / 14592u;          // NT32*64
                unsigned rem = id % 14592u;
                unsigned kb  = rem >> 6, sl = rem & 63u;
                unsigned r16 = sl >> 2;
                unsigned c   = (sl & 3u) ^ (((r16 >> 3) & 1u) << 1);
                unsigned row = rb * 16u + r16;
                bf16x8 v = {};
                if (row < N_DIM) {
                    if (kb < 224u) {
                        unsigned k = kb * 32u + c * 8u;
                        const float* p = W + (size_t)row * H_DIM + k;
                        f32x4 a = *(const f32x4*)p;
                        f32x4 b = *(const f32x4*)(p + 4);
                        v = pack8(a, b);
                    } else {
                        unsigned kl = (kb - 224u) * 32u + c * 8u;   // 0..127
                        const bool s1 = row >= D0_DIM;
                        const unsigned lo = s1 ? 64u : 0u;
                        if (kl >= lo && kl < lo + 64u) {
                            const float* p = Bbuf + ((size_t)(s1 ? 1u : 0u) * D0_DIM +
                                                     (row - (s1 ? D0_DIM : 0u))) * R_DIM + (kl - lo);
                            f32x4 a = *(const f32x4*)p;
                            f32x4 b = *(const f32x4*)(p + 4);
                            v = pack8(a, b);
                        }
                    }
                }
                *(bf16x8*)(we + ((size_t)rb * NT32 + kb) * 512u + sl * 8u) = v;
            }
        }
        return;
    }

    // ---- lora_a + convert_x ----
    __shared__ __align__(16) short sX[2][128 * 40];
    __shared__ __align__(16) short sA[2][128 * 40];

    const int bx = blockIdx.x - CONV_BLKS;     // 0..511
    const int tid = threadIdx.x;
    const int m0 = (bx >> 3) * 128;
    const int k0 = (bx & 7) * KCHUNK;
    const int wave = tid >> 6, lane = tid & 63;
    const int wm = (wave & 1) * 64, wn = (wave >> 1) * 64;
    const int fr = lane & 15, fq = lane >> 4;

    f32x4 acc[4][4] = {};

    const int srow = tid >> 1, shalf = (tid & 1) * 16;
    const float* xP = x + (size_t)(m0 + srow) * H_DIM + k0 + shalf;
    const float* aP = A + (size_t)srow * H_DIM + k0 + shalf;

    // tiled-swizzled xe destination
    const unsigned rbx = (unsigned)(m0 + srow) >> 4;
    const unsigned r16 = (unsigned)srow & 15u;
    const unsigned kb0 = (unsigned)k0 >> 5;
    const unsigned c0  = (unsigned)shalf >> 3;       // 0 or 2
    const unsigned sx  = ((r16 >> 3) & 1u) << 1;
    const unsigned sl0 = r16 * 4u + (c0 ^ sx);
    const unsigned sl1 = r16 * 4u + ((c0 + 1u) ^ sx);
    short* xeB = xe + ((size_t)rbx * NT32 + kb0) * 512u;

    const int swoff = srow * 40 + shalf;
    const int xr_off = (wm + fr) * 40 + fq * 8;
    const int ar_off = (wn + fr) * 40 + fq * 8;

    // preload iter 0
    f32x4 cx0 = *(const f32x4*)(xP);
    f32x4 cx1 = *(const f32x4*)(xP + 4);
    f32x4 cx2 = *(const f32x4*)(xP + 8);
    f32x4 cx3 = *(const f32x4*)(xP + 12);
    f32x4 ca0 = *(const f32x4*)(aP);
    f32x4 ca1 = *(const f32x4*)(aP + 4);
    f32x4 ca2 = *(const f32x4*)(aP + 8);
    f32x4 ca3 = *(const f32x4*)(aP + 12);
    f32x4 nx0 = {}, nx1 = {}, nx2 = {}, nx3 = {};
    f32x4 na0 = {}, na1 = {}, na2 = {}, na3 = {};

#pragma unroll 1
    for (int it = 0; it < KCHUNK / 32; ++it) {
        if (it < KCHUNK / 32 - 1) {
            const float* px = xP + (it + 1) * 32;
            const float* pa = aP + (it + 1) * 32;
            nx0 = *(const f32x4*)(px);
            nx1 = *(const f32x4*)(px + 4);
            nx2 = *(const f32x4*)(px + 8);
            nx3 = *(const f32x4*)(px + 12);
            na0 = *(const f32x4*)(pa);
            na1 = *(const f32x4*)(pa + 4);
            na2 = *(const f32x4*)(pa + 8);
            na3 = *(const f32x4*)(pa + 12);
        }
        bf16x8 px0 = pack8(cx0, cx1), px1 = pack8(cx2, cx3);
        bf16x8 pa0 = pack8(ca0, ca1), pa1 = pack8(ca2, ca3);

        // fused convert_x: tiled-swizzled store to xe
        *(bf16x8*)(xeB + (size_t)it * 512 + sl0 * 8u) = px0;
        *(bf16x8*)(xeB + (size_t)it * 512 + sl1 * 8u) = px1;

        short* bX = &sX[it & 1][0];
        short* bA = &sA[it & 1][0];
        *(bf16x8*)(bX + swoff) = px0; *(bf16x8*)(bX + swoff + 8) = px1;
        *(bf16x8*)(bA + swoff) = pa0; *(bf16x8*)(bA + swoff + 8) = pa1;

        asm volatile("s_waitcnt lgkmcnt(0)" ::: "memory");
        __builtin_amdgcn_s_barrier();
        __builtin_amdgcn_sched_barrier(0);

        bf16x8 af[4], bfg[4];
#pragma unroll
        for (int i = 0; i < 4; ++i) af[i] = *(const bf16x8*)(bX + xr_off + i * 640);
#pragma unroll
        for (int i = 0; i < 4; ++i) bfg[i] = *(const bf16x8*)(bA + ar_off + i * 640);
#pragma unroll
        for (int mi = 0; mi < 4; ++mi)
#pragma unroll
            for (int ni = 0; ni < 4; ++ni)
                acc[mi][ni] = __builtin_amdgcn_mfma_f32_16x16x32_bf16(
                    af[mi], bfg[ni], acc[mi][ni], 0, 0, 0);

        cx0 = nx0; cx1 = nx1; cx2 = nx2; cx3 = nx3;
        ca0 = na0; ca1 = na1; ca2 = na2; ca3 = na3;
    }

    // partial-sum epilogue: fp32 atomics into la (8 k-split adders/elem)
#pragma unroll
    for (int ni = 0; ni < 4; ++ni) {
        const int col = wn + ni * 16 + fr;
#pragma unroll
        for (int mi = 0; mi < 4; ++mi) {
            const int row = m0 + wm + mi * 16 + fq * 4;
#pragma unroll
            for (int r = 0; r < 4; ++r)
                atomicAdd(&la[(size_t)(row + r) * LA_WIDTH + col], acc[mi][ni][r]);
        }
    }
}

// la_to_xe: la fp32 [S][128] -> bf16 -> xe kblocks 224..227 (swizzled slots)
__global__ __launch_bounds__(256)
void la_to_xe(const float* __restrict__ la, short* __restrict__ xe) {
    unsigned id = blockIdx.x * 256u + threadIdx.x;   // < 8192*16
    unsigned row = id >> 4, c8 = (id & 15u) * 8u;
    const float* p = la + (size_t)row * LA_WIDTH + c8;
    f32x4 s0 = *(const f32x4*)(p);
    f32x4 s1 = *(const f32x4*)(p + 4);
    unsigned rbx = row >> 4, r16 = row & 15u;
    unsigned kb = 224u + (c8 >> 5);
    unsigned cc = (c8 >> 3) & 3u;
    unsigned sl = r16 * 4u + (cc ^ (((r16 >> 3) & 1u) << 1));
    *(bf16x8*)(xe + ((size_t)rbx * NT32 + kb) * 512u + sl * 8u) = pack8(s0, s1);
}

// one MFMA row: acc[m][0..3] += af x brf0..3
#define MFMA_ROW(m, a)                                                          \
    acc[m][0] = __builtin_amdgcn_mfma_f32_16x16x32_bf16(a, brf0, acc[m][0], 0, 0, 0); \
    acc[m][1] = __builtin_amdgcn_mfma_f32_16x16x32_bf16(a, brf1, acc[m][1], 0, 0, 0); \
    acc[m][2] = __builtin_amdgcn_mfma_f32_16x16x32_bf16(a, brf2, acc[m][2], 0, 0, 0); \
    acc[m][3] = __builtin_amdgcn_mfma_f32_16x16x32_bf16(a, brf3, acc[m][3], 0, 0, 0)

// ---------------------------------------------------------------------------
// main_gemm_tiled: out = xext @ Wext^T + bias  (K = 7296 includes LoRA-B)
// ROUND 6: ring-3 frame restored (round-3 verified best: 72 KB LDS, (256,2),
// one barrier/step, counted vmcnt(6), m201 swizzle, XCD-chunking), with the
// K-step inner loop restructured into a FINE-GRAINED 5-region interleave
// (the m196/m201 lever): each MFMA cluster (8 mfma) overlaps the NEXT
// cluster's ds_reads and a slice of the tile-kt+2 DMA issue. Region
// boundaries pinned with sched_barrier(0); the compiler then emits counted
// lgkmcnt(N) waits (never a full drain) because issue order is known.
// Ring-3 write-safety: DMA targets (kt+2)%3, whose last reads retired
// before the step-kt barrier (single barrier per step, rounds 1-3 proven).
// ---------------------------------------------------------------------------
__global__ __launch_bounds__(256, 2)
void main_gemm_tiled(const short* __restrict__ xe, const short* __restrict__ we,
                     const float* __restrict__ bias, float* __restrict__ out) {
    __shared__ __align__(16) short lds[3 * 12288];   // 3 bufs x (A 16KB | B 8KB)

    const int tid = threadIdx.x;
    const int bx = blockIdx.x;                 // 0..543
    const int xcd = bx & 7, p = bx >> 3;
    const int tile = xcd * 68 + p;             // 544 = 8 * 68 exactly
    const int m0 = (tile / 17) * 256;
    const int n0 = (tile % 17) * 128;

    const int wave = tid >> 6, lane = tid & 63;
    const int wm = (wave & 1) * 128;
    const int wn = (wave >> 1) * 64;
    const int fr = lane & 15, fq = lane >> 4;

    f32x4 acc[8][4] = {};

    // per-tile staging: 24 x 1KB blocks (A rblocks 0..15, B rblocks 0..7);
    // wave w issues 6 contiguous-source global_load_lds.
    const short* gp[6];
    int ldoff[6];
    {
        const short* xe_pan = xe + (size_t)(m0 >> 4) * NT32 * 512 + lane * 8;
        const short* we_pan = we + (size_t)(n0 >> 4) * NT32 * 512 + lane * 8;
#pragma unroll
        for (int i = 0; i < 6; ++i) {
            const int idx = wave * 6 + i;
            if (idx < 16) { gp[i] = xe_pan + (size_t)idx * NT32 * 512; ldoff[i] = idx * 512; }
            else          { gp[i] = we_pan + (size_t)(idx - 16) * NT32 * 512; ldoff[i] = 8192 + (idx - 16) * 512; }
        }
    }

    // swizzled fragment read offsets (shorts): row*32 + (fq ^ ((row>>3)&1)<<1)*8
    const int swz  = (fq ^ ((fr >> 3) << 1)) * 8;
    const int aoff = (wm + fr) * 32 + swz;
    const int boff = 8192 + (wn + fr) * 32 + swz;

    // prologue: tile 0 -> buf 0, tile 1 -> buf 1 (12 loads in flight)
#pragma unroll
    for (int i = 0; i < 6; ++i) gload_lds16(gp[i], lds + ldoff[i]);
#pragma unroll
    for (int i = 0; i < 6; ++i) gload_lds16(gp[i] + 512, lds + 12288 + ldoff[i]);

    int bufo = 0;           // read-buffer offset (shorts): tile kt
    int dbufo = 2 * 12288;  // stage-buffer offset: tile kt+2
    int toff = 2 * 512;     // global offset (shorts) of tile kt+2

#pragma unroll 1
    for (int kt = 0; kt < NT32; ++kt) {
        const short* pa = lds + bufo + aoff;
        const short* pb = lds + bufo + boff;
        short* st = lds + dbufo;
        const int go = toff;

        // counted wait: tile kt's 6 loads are the oldest of 12 outstanding
        asm volatile("s_waitcnt vmcnt(6)" ::: "memory");
        __builtin_amdgcn_s_barrier();
        __builtin_amdgcn_sched_barrier(0);

        // R0: B-fragments + first A-pair ; DMA 0,1
        bf16x8 brf0 = *(const bf16x8*)(pb);
        bf16x8 brf1 = *(const bf16x8*)(pb + 512);
        bf16x8 brf2 = *(const bf16x8*)(pb + 1024);
        bf16x8 brf3 = *(const bf16x8*)(pb + 1536);
        bf16x8 af0  = *(const bf16x8*)(pa);
        bf16x8 af1  = *(const bf16x8*)(pa + 512);
        gload_lds16(gp[0] + go, st + ldoff[0]);
        gload_lds16(gp[1] + go, st + ldoff[1]);
        __builtin_amdgcn_sched_barrier(0);

        // R1: reads for next cluster + DMA 2,3 + MFMA m0,m1
        bf16x8 af2 = *(const bf16x8*)(pa + 1024);
        bf16x8 af3 = *(const bf16x8*)(pa + 1536);
        gload_lds16(gp[2] + go, st + ldoff[2]);
        gload_lds16(gp[3] + go, st + ldoff[3]);
        __builtin_amdgcn_s_setprio(1);
        MFMA_ROW(0, af0);
        MFMA_ROW(1, af1);
        __builtin_amdgcn_s_setprio(0);
        __builtin_amdgcn_sched_barrier(0);

        // R2: reads + DMA 4,5 + MFMA m2,m3
        bf16x8 af4 = *(const bf16x8*)(pa + 2048);
        bf16x8 af5 = *(const bf16x8*)(pa + 2560);
        gload_lds16(gp[4] + go, st + ldoff[4]);
        gload_lds16(gp[5] + go, st + ldoff[5]);
        __builtin_amdgcn_s_setprio(1);
        MFMA_ROW(2, af2);
        MFMA_ROW(3, af3);
        __builtin_amdgcn_s_setprio(0);
        __builtin_amdgcn_sched_barrier(0);

        // R3: last reads + MFMA m4,m5
        bf16x8 af6 = *(const bf16x8*)(pa + 3072);
        bf16x8 af7 = *(const bf16x8*)(pa + 3584);
        __builtin_amdgcn_s_setprio(1);
        MFMA_ROW(4, af4);
        MFMA_ROW(5, af5);
        __builtin_amdgcn_s_setprio(0);
        __builtin_amdgcn_sched_barrier(0);

        // R4: MFMA m6,m7
        __builtin_amdgcn_s_setprio(1);
        MFMA_ROW(6, af6);
        MFMA_ROW(7, af7);
        __builtin_amdgcn_s_setprio(0);
        __builtin_amdgcn_sched_barrier(0);

        // advance ring (tail DMAs wrap to tile 0/1: dummy re-stage, harmless)
        bufo += 12288;  if (bufo == 3 * 12288) bufo = 0;
        dbufo += 12288; if (dbufo == 3 * 12288) dbufo = 0;
        toff += 512;    if (toff == NT32 * 512) toff = 0;
    }
    asm volatile("s_waitcnt vmcnt(0)" ::: "memory");

    // epilogue: + bias, fp32 store. C/D: col = lane&15, row = fq*4 + r
#pragma unroll
    for (int n = 0; n < 4; ++n) {
        const int col = n0 + wn + n * 16 + fr;
        if (col < N_DIM) {
            const float bv = bias[col];
#pragma unroll
            for (int m = 0; m < 8; ++m) {
                const int row = m0 + wm + m * 16 + fq * 4;
#pragma unroll
                for (int r = 0; r < 4; ++r)
                    out[(size_t)(row + r) * N_DIM + col] = acc[m][n][r] + bv;
            }
        }
    }
}

// ===========================================================================
// Fallback (round-1 proven path) if workspace is too small for bf16 staging
// ===========================================================================
__global__ __launch_bounds__(256, 2)
void lora_a_gemm(const float* __restrict__ x, const float* __restrict__ Abuf,
                 float* __restrict__ la) {
    __shared__ __align__(16) short sX[32 * 40];
    __shared__ __align__(16) short sA[128 * 40];
    const int tid = threadIdx.x;
    const int m0 = blockIdx.x * 32;
    const int wave = tid >> 6, lane = tid & 63;
    const int fr = lane & 15, fq = lane >> 4;
    const int wn = wave * 32;
    f32x4 acc[2][2] = {};
    const int xrow = tid >> 3, xcol = (tid & 7) * 4;
    const float* xP = x + (size_t)(m0 + xrow) * H_DIM + xcol;
    short* sXw = sX + xrow * 40 + xcol;
    const int arow = tid >> 1, ahalf = (tid & 1) * 16;
    const float* aP = Abuf + (size_t)arow * H_DIM + ahalf;
    short* sAw = sA + arow * 40 + ahalf;
    const short* sXr = sX + fr * 40 + fq * 8;
    const short* sAr = sA + (wn + fr) * 40 + fq * 8;
    for (int kt = 0; kt < H_DIM / 32; ++kt) {
        f32x4 xv = *(const f32x4*)(xP + kt * 32);
        f32x4 a0 = *(const f32x4*)(aP + kt * 32);
        f32x4 a1 = *(const f32x4*)(aP + kt * 32 + 4);
        f32x4 a2 = *(const f32x4*)(aP + kt * 32 + 8);
        f32x4 a3 = *(const f32x4*)(aP + kt * 32 + 12);
        bf16x4 xs;
        xs[0] = f2bf(xv[0]); xs[1] = f2bf(xv[1]);
        xs[2] = f2bf(xv[2]); xs[3] = f2bf(xv[3]);
        bf16x8 as0 = pack8(a0, a1), as1 = pack8(a2, a3);
        __syncthreads();
        *(bf16x4*)(sXw) = xs;
        *(bf16x8*)(sAw) = as0;
        *(bf16x8*)(sAw + 8) = as1;
        __syncthreads();
        bf16x8 xf0 = *(const bf16x8*)(sXr);
        bf16x8 xf1 = *(const bf16x8*)(sXr + 16 * 40);
        bf16x8 af0 = *(const bf16x8*)(sAr);
        bf16x8 af1 = *(const bf16x8*)(sAr + 16 * 40);
        acc[0][0] = __builtin_amdgcn_mfma_f32_16x16x32_bf16(xf0, af0, acc[0][0], 0, 0, 0);
        acc[0][1] = __builtin_amdgcn_mfma_f32_16x16x32_bf16(xf0, af1, acc[0][1], 0, 0, 0);
        acc[1][0] = __builtin_amdgcn_mfma_f32_16x16x32_bf16(xf1, af0, acc[1][0], 0, 0, 0);
        acc[1][1] = __builtin_amdgcn_mfma_f32_16x16x32_bf16(xf1, af1, acc[1][1], 0, 0, 0);
    }
#pragma unroll
    for (int ni = 0; ni < 2; ++ni) {
        const int col = wn + ni * 16 + fr;
#pragma unroll
        for (int mi = 0; mi < 2; ++mi) {
            const int row = m0 + mi * 16 + fq * 4;
#pragma unroll
            for (int r = 0; r < 4; ++r)
                la[(size_t)(row + r) * LA_WIDTH + col] = acc[mi][ni][r];
        }
    }
}

#define LDS_STRIDE 40
__global__ __launch_bounds__(256, 2)
void main_gemm(const float* __restrict__ x, const float* __restrict__ W,
               const float* __restrict__ bias, const float* __restrict__ Bbuf,
               const float* __restrict__ la, float* __restrict__ out) {
    __shared__ __align__(16) short sA[128 * LDS_STRIDE];
    __shared__ __align__(16) short sB[128 * LDS_STRIDE];
    const int tid = threadIdx.x;
    const int n0 = blockIdx.x * 128, m0 = blockIdx.y * 128;
    const int wave = tid >> 6, lane = tid & 63;
    const int wm = (wave & 1) * 64, wn = (wave >> 1) * 64;
    const int fr = lane & 15, fq = lane >> 4;
    f32x4 acc[4][4] = {};
    const int srow = tid >> 1, shalf = (tid & 1) * 16;
    const float* xP = x + (size_t)(m0 + srow) * H_DIM + shalf;
    const int wRow = n0 + srow;
    const bool wValid = wRow < N_DIM;
    const float* wP = W + (size_t)wRow * H_DIM + shalf;
    const int slice = (n0 >= D0_DIM) ? 1 : 0;
    const int oCol = wRow - slice * D0_DIM;
    const bool bValid = wValid && (oCol < (slice ? D1_DIM : D0_DIM));
    const float* laP = la + (size_t)(m0 + srow) * LA_WIDTH + slice * R_DIM + shalf;
    const float* bP = Bbuf + ((size_t)slice * D0_DIM + oCol) * R_DIM + shalf;
    short* sAw = sA + srow * LDS_STRIDE + shalf;
    short* sBw = sB + srow * LDS_STRIDE + shalf;
    const short* sAr = sA + (wm + fr) * LDS_STRIDE + fq * 8;
    const short* sBr = sB + (wn + fr) * LDS_STRIDE + fq * 8;
    const int KT = H_DIM / 32;
    for (int it = 0; it < KT + 2; ++it) {
        const float *pa, *pb;
        bool vb;
        if (it < KT) { pa = xP + it * 32; pb = wP + it * 32; vb = wValid; }
        else { const int lt = it - KT; pa = laP + lt * 32; pb = bP + lt * 32; vb = bValid; }
        f32x4 a0 = *(const f32x4*)(pa);
        f32x4 a1 = *(const f32x4*)(pa + 4);
        f32x4 a2 = *(const f32x4*)(pa + 8);
        f32x4 a3 = *(const f32x4*)(pa + 12);
        f32x4 z = {0.f, 0.f, 0.f, 0.f};
        f32x4 b0 = z, b1 = z, b2 = z, b3 = z;
        if (vb) {
            b0 = *(const f32x4*)(pb); b1 = *(const f32x4*)(pb + 4);
            b2 = *(const f32x4*)(pb + 8); b3 = *(const f32x4*)(pb + 12);
        }
        bf16x8 pa0 = pack8(a0, a1), pa1 = pack8(a2, a3);
        bf16x8 pb0 = pack8(b0, b1), pb1 = pack8(b2, b3);
        __syncthreads();
        *(bf16x8*)(sAw) = pa0; *(bf16x8*)(sAw + 8) = pa1;
        *(bf16x8*)(sBw) = pb0; *(bf16x8*)(sBw + 8) = pb1;
        __syncthreads();
        bf16x8 af[4], bfg[4];
#pragma unroll
        for (int i = 0; i < 4; ++i) af[i] = *(const bf16x8*)(sAr + i * 16 * LDS_STRIDE);
#pragma unroll
        for (int i = 0; i < 4; ++i) bfg[i] = *(const bf16x8*)(sBr + i * 16 * LDS_STRIDE);
#pragma unroll
        for (int mi = 0; mi < 4; ++mi)
#pragma unroll
            for (int ni = 0; ni < 4; ++ni)
                acc[mi][ni] = __builtin_amdgcn_mfma_f32_16x16x32_bf16(
                    af[mi], bfg[ni], acc[mi][ni], 0, 0, 0);
    }
#pragma unroll
    for (int ni = 0; ni < 4; ++ni) {
        const int col = n0 + wn + ni * 16 + fr;
        if (col < N_DIM) {
            const float bv = bias[col];
#pragma unroll
            for (int mi = 0; mi < 4; ++mi) {
                const int row = m0 + wm + mi * 16 + fq * 4;
#pragma unroll
                for (int r = 0; r < 4; ++r)
                    out[(size_t)(row + r) * N_DIM + col] = acc[mi][ni][r] + bv;
            }
        }
    }
}

extern "C" void kernel_launch(void* const* d_in, const int* in_sizes, int n_in,
                              void* d_out, int out_size, void* d_ws, size_t ws_size,
                              hipStream_t stream) {
    const float* x    = (const float*)d_in[0];
    const float* W    = (const float*)d_in[1];
    const float* bias = (const float*)d_in[2];
    const float* A    = (const float*)d_in[3];
    const float* B    = (const float*)d_in[4];
    float* out = (float*)d_out;

    const size_t xe_bytes = (size_t)XE_RB * NT32 * 1024;   // 119,537,664
    const size_t we_bytes = (size_t)WE_RB * NT32 * 1024;   //  31,752,192
    const size_t la_bytes = (size_t)S_DIM * LA_WIDTH * 4;  //   4,194,304

    if (ws_size >= xe_bytes + we_bytes) {
        short* xe = (short*)d_ws;
        short* we = (short*)((char*)d_ws + xe_bytes);
        // la scratch lives in the HEAD of the output buffer: zeroed here,
        // accumulated by fused_stage1, consumed by la_to_xe, then fully
        // overwritten by main_gemm_tiled's epilogue.
        float* la = (float*)d_out;

        hipMemsetAsync(d_out, 0, la_bytes, stream);
        fused_stage1<<<dim3(CONV_BLKS + 512), dim3(256), 0, stream>>>(
            x, W, A, B, la, xe, we);
        la_to_xe<<<dim3(S_DIM * 16 / 256), dim3(256), 0, stream>>>(la, xe);
        main_gemm_tiled<<<dim3(32 * 17), dim3(256), 0, stream>>>(xe, we, bias, out);
    } else {
        float* la = (float*)d_ws;   // 4 MB scratch
        lora_a_gemm<<<dim3(S_DIM / 32), dim3(256), 0, stream>>>(x, A, la);
        main_gemm<<<dim3(N_DIM / 128 + 1, S_DIM / 128), dim3(256), 0, stream>>>(
            x, W, bias, B, la, out);
    }
}